// Round 15
// baseline (197.904 us; speedup 1.0000x reference)
//
#include <hip/hip_runtime.h>

// All tensors FLOAT32 (proven R5). GEMMs: bf16 MFMA (err 0.031 < 0.108 thr).
// Interp: brute force, VALU-issue-bound (R14: 75% VALUBusy). d2 exact rn
// ((dx2+dy2)+dz2, no FMA); strict-< insertion + ascending enumeration ==
// lax.top_k stable tie-break. R15: 2 candidates/iter (j before j+1 keeps tie
// order), LDS pad [8][33][3] kills the 8-way pl-stride conflict (737k -> ~0).
// Harness floor measured: ~46us ws-poison fill + restores + ~3us/launch.

typedef __attribute__((ext_vector_type(8))) short bf16x8;
typedef __attribute__((ext_vector_type(4))) float f32x4;

__device__ __forceinline__ unsigned short f2bf(float f) {
    union { float f; unsigned u; } v; v.f = f;
    return (unsigned short)((v.u + 0x7fffu + ((v.u >> 16) & 1u)) >> 16); // RNE
}
__device__ __forceinline__ unsigned pack2(float a, float b) {
    return (unsigned)f2bf(a) | ((unsigned)f2bf(b) << 16);
}

// ---------- prep: xyz -> padded float4, zero BN-stat accumulators ----------
__global__ __launch_bounds__(256)
void prep_kernel(const float* __restrict__ p1, const float* __restrict__ p2,
                 const float* __restrict__ p4,
                 float4* __restrict__ x1, float4* __restrict__ x2, float4* __restrict__ x4,
                 float* __restrict__ st1, float* __restrict__ st2) {
    int i = blockIdx.x * 256 + threadIdx.x;
    if (i < 256) { st1[i] = 0.f; st2[i] = 0.f; }
    const int P1 = 16384, P2 = 8192, P4 = 4096;
    if (i < P1) {
        x1[i] = make_float4(p1[i*3], p1[i*3+1], p1[i*3+2], 0.f);
    } else if (i < P1 + P2) {
        int j = i - P1;
        x2[j] = make_float4(p2[j*3], p2[j*3+1], p2[j*3+2], 0.f);
    } else if (i < P1 + P2 + P4) {
        int j = i - P1 - P2;
        x4[j] = make_float4(p4[j*3], p4[j*3+1], p4[j*3+2], 0.f);
    }
}

// ---------- 3-NN interpolate: 8 targets x 32 chunks, 2 candidates/iter ----------
template<int CHUNK>
__global__ __launch_bounds__(256)
void nn_interp_kernel(const float4* __restrict__ tgt, int Nt,
                      const float4* __restrict__ src, int Ns,
                      const float* __restrict__ feats,
                      float* __restrict__ out) {
    int tid = threadIdx.x;
    int pl = tid & 7, ch = tid >> 3;
    int b = blockIdx.y;
    int tbase = blockIdx.x * 8;
    float4 ta = tgt[b * Nt + tbase + pl];

    float a0=3.4e38f, a1=3.4e38f, a2=3.4e38f;
    int ia0=0, ia1=0, ia2=0;
    const float4* sp = src + b * Ns + ch * CHUNK;
    #pragma unroll 4
    for (int j = 0; j < CHUNK; j += 2) {
        float4 sA = sp[j];
        float4 sB = sp[j + 1];
        // two independent exact-rn distances (ILP / possible v_pk packing)
        float dxA = ta.x - sA.x, dyA = ta.y - sA.y, dzA = ta.z - sA.z;
        float dxB = ta.x - sB.x, dyB = ta.y - sB.y, dzB = ta.z - sB.z;
        float d2A = __fadd_rn(__fadd_rn(__fmul_rn(dxA,dxA), __fmul_rn(dyA,dyA)),
                              __fmul_rn(dzA,dzA));
        float d2B = __fadd_rn(__fadd_rn(__fmul_rn(dxB,dxB), __fmul_rn(dyB,dyB)),
                              __fmul_rn(dzB,dzB));
        // insert j first, then j+1 -- preserves earliest-index-wins exactly
        {
            int idx = ch * CHUNK + j;
            bool c0 = d2A < a0, c1 = d2A < a1, c2 = d2A < a2;
            float na2 = fminf(a2, fmaxf(a1, d2A));
            float na1 = __builtin_amdgcn_fmed3f(a0, a1, d2A);
            float na0 = fminf(a0, d2A);
            ia2 = c1 ? ia1 : (c2 ? idx : ia2);
            ia1 = c0 ? ia0 : (c1 ? idx : ia1);
            ia0 = c0 ? idx : ia0;
            a0 = na0; a1 = na1; a2 = na2;
        }
        {
            int idx = ch * CHUNK + j + 1;
            bool c0 = d2B < a0, c1 = d2B < a1, c2 = d2B < a2;
            float na2 = fminf(a2, fmaxf(a1, d2B));
            float na1 = __builtin_amdgcn_fmed3f(a0, a1, d2B);
            float na0 = fminf(a0, d2B);
            ia2 = c1 ? ia1 : (c2 ? idx : ia2);
            ia1 = c0 ? ia0 : (c1 ? idx : ia1);
            ia0 = c0 ? idx : ia0;
            a0 = na0; a1 = na1; a2 = na2;
        }
    }

    __shared__ float sd[8][33][3];   // pad 32->33: pl stride 99 (==3 mod 32)
    __shared__ int   si[8][33][3];
    __shared__ float pd[8][4][3];
    __shared__ int   pi[8][4][3];
    __shared__ float sw[8][3];
    __shared__ int   sg[8][3];
    sd[pl][ch][0]=a0; sd[pl][ch][1]=a1; sd[pl][ch][2]=a2;
    si[pl][ch][0]=ia0; si[pl][ch][1]=ia1; si[pl][ch][2]=ia2;
    __syncthreads();

    // level 1: 32 threads = 8 targets x 4 mergers; each merges 8 chunks ascending
    if (tid < 32) {
        int tt = tid >> 2, m = tid & 3;
        float m0=3.4e38f, m1=3.4e38f, m2=3.4e38f;
        int j0=0, j1=0, j2=0;
        #pragma unroll
        for (int cc = m * 8; cc < m * 8 + 8; ++cc) {
            #pragma unroll
            for (int k = 0; k < 3; ++k) {
                float d = sd[tt][cc][k]; int ix = si[tt][cc][k];
                bool c0 = d < m0, c1 = d < m1, c2 = d < m2;
                m2 = c1 ? m1 : (c2 ? d : m2);  j2 = c1 ? j1 : (c2 ? ix : j2);
                m1 = c0 ? m0 : (c1 ? d : m1);  j1 = c0 ? j0 : (c1 ? ix : j1);
                m0 = c0 ? d : m0;              j0 = c0 ? ix : j0;
            }
        }
        pd[tt][m][0]=m0; pd[tt][m][1]=m1; pd[tt][m][2]=m2;
        pi[tt][m][0]=j0; pi[tt][m][1]=j1; pi[tt][m][2]=j2;
    }
    __syncthreads();

    // level 2: 8 threads merge 4 partials ascending, compute weights
    if (tid < 8) {
        float m0=3.4e38f, m1=3.4e38f, m2=3.4e38f;
        int j0=0, j1=0, j2=0;
        #pragma unroll
        for (int m = 0; m < 4; ++m) {
            #pragma unroll
            for (int k = 0; k < 3; ++k) {
                float d = pd[tid][m][k]; int ix = pi[tid][m][k];
                bool c0 = d < m0, c1 = d < m1, c2 = d < m2;
                m2 = c1 ? m1 : (c2 ? d : m2);  j2 = c1 ? j1 : (c2 ? ix : j2);
                m1 = c0 ? m0 : (c1 ? d : m1);  j1 = c0 ? j0 : (c1 ? ix : j1);
                m0 = c0 ? d : m0;              j0 = c0 ? ix : j0;
            }
        }
        float d0 = sqrtf(fmaxf(m0, 0.f));
        float d1 = sqrtf(fmaxf(m1, 0.f));
        float d2 = sqrtf(fmaxf(m2, 0.f));
        float w0 = 1.f / (d0 + 1e-8f);
        float w1 = 1.f / (d1 + 1e-8f);
        float w2 = 1.f / (d2 + 1e-8f);
        float wsum = w0 + w1 + w2;
        sw[tid][0] = w0 / wsum; sw[tid][1] = w1 / wsum; sw[tid][2] = w2 / wsum;
        sg[tid][0] = j0; sg[tid][1] = j1; sg[tid][2] = j2;
    }
    __syncthreads();

    // gather: 8 targets x 64 channel-pairs
    for (int e = tid; e < 8 * 64; e += 256) {
        int tt = e >> 6, cp = (e & 63) * 2;
        int base = b * Ns * 128;
        float2 f0  = *(const float2*)&feats[base + sg[tt][0] * 128 + cp];
        float2 f1  = *(const float2*)&feats[base + sg[tt][1] * 128 + cp];
        float2 f2v = *(const float2*)&feats[base + sg[tt][2] * 128 + cp];
        float2 o;
        o.x = sw[tt][0] * f0.x + sw[tt][1] * f1.x + sw[tt][2] * f2v.x;
        o.y = sw[tt][0] * f0.y + sw[tt][1] * f1.y + sw[tt][2] * f2v.y;
        *(float2*)&out[(b * Nt + tbase + tt) * 128 + cp] = o;
    }
}

// ---------- GEMM A (MFMA bf16, +fused BN stats): H = [L|R] @ W^T ---------- (R9-proven)
__global__ __launch_bounds__(256)
void gemm_a_kernel(const float* __restrict__ L, const float* __restrict__ R,
                   const float* __restrict__ W, float* __restrict__ H,
                   float* __restrict__ st) {
    __shared__ short Asm[4096];
    __shared__ short Bsm[2048];
    int tid = threadIdx.x;
    int lane = tid & 63, w = tid >> 6;
    int m16 = lane & 15, quad = lane >> 4;
    int rowBase = blockIdx.y * 128;
    int colBase = blockIdx.x * 64;
    f32x4 acc[2][4] = {};
    for (int k0 = 0; k0 < 256; k0 += 32) {
        #pragma unroll
        for (int i = 0; i < 2; ++i) {
            int u = tid + i * 256;
            int r = u >> 2, g = u & 3;
            const float* p = (k0 < 128) ? &L[(rowBase + r) * 128 + k0 + g * 8]
                                        : &R[(rowBase + r) * 128 + (k0 - 128) + g * 8];
            float4 x = *(const float4*)p, y = *(const float4*)(p + 4);
            uint4 pk = make_uint4(pack2(x.x, x.y), pack2(x.z, x.w),
                                  pack2(y.x, y.y), pack2(y.z, y.w));
            int blk = (r >> 4) * 64 + (r & 15) * 4 + g;
            *(uint4*)&Asm[blk * 8] = pk;
        }
        {
            int n = tid >> 2, g = tid & 3;
            const float* p = &W[(colBase + n) * 256 + k0 + g * 8];
            float4 x = *(const float4*)p, y = *(const float4*)(p + 4);
            uint4 pk = make_uint4(pack2(x.x, x.y), pack2(x.z, x.w),
                                  pack2(y.x, y.y), pack2(y.z, y.w));
            int blk = (n >> 4) * 64 + (n & 15) * 4 + g;
            *(uint4*)&Bsm[blk * 8] = pk;
        }
        __syncthreads();
        bf16x8 a0 = *(const bf16x8*)&Asm[((2 * w + 0) * 64 + m16 * 4 + quad) * 8];
        bf16x8 a1 = *(const bf16x8*)&Asm[((2 * w + 1) * 64 + m16 * 4 + quad) * 8];
        #pragma unroll
        for (int ct = 0; ct < 4; ++ct) {
            bf16x8 bf = *(const bf16x8*)&Bsm[(ct * 64 + m16 * 4 + quad) * 8];
            acc[0][ct] = __builtin_amdgcn_mfma_f32_16x16x32_bf16(a0, bf, acc[0][ct], 0, 0, 0);
            acc[1][ct] = __builtin_amdgcn_mfma_f32_16x16x32_bf16(a1, bf, acc[1][ct], 0, 0, 0);
        }
        __syncthreads();
    }
    #pragma unroll
    for (int rt = 0; rt < 2; ++rt)
        #pragma unroll
        for (int r = 0; r < 4; ++r) {
            int row = rowBase + (2 * w + rt) * 16 + quad * 4 + r;
            #pragma unroll
            for (int ct = 0; ct < 4; ++ct)
                H[row * 128 + colBase + ct * 16 + m16] = acc[rt][ct][r];
        }
    float* ssum = (float*)Asm;
    float* ssq  = (float*)Asm + 1024;
    #pragma unroll
    for (int ct = 0; ct < 4; ++ct) {
        float s = 0.f, q = 0.f;
        #pragma unroll
        for (int rt = 0; rt < 2; ++rt)
            #pragma unroll
            for (int r = 0; r < 4; ++r) {
                float v = acc[rt][ct][r];
                s += v; q += v * v;
            }
        ssum[(w * 4 + quad) * 64 + ct * 16 + m16] = s;
        ssq [(w * 4 + quad) * 64 + ct * 16 + m16] = q;
    }
    __syncthreads();
    if (tid < 64) {
        float s = 0.f, q = 0.f;
        #pragma unroll
        for (int i = 0; i < 16; ++i) { s += ssum[i * 64 + tid]; q += ssq[i * 64 + tid]; }
        atomicAdd(&st[colBase + tid], s);
        atomicAdd(&st[128 + colBase + tid], q);
    }
}

// ---------- GEMM B (MFMA bf16, finalize fused) ---------- (R12/R13-proven)
__global__ __launch_bounds__(256)
void gemm_b_kernel(const float* __restrict__ Hin, const float* __restrict__ st,
                   const float* __restrict__ gam, const float* __restrict__ bet,
                   float invN, const float* __restrict__ W,
                   const float* __restrict__ bias, float* __restrict__ out) {
    __shared__ short Asm[4096];
    __shared__ short Bsm[2048];
    __shared__ float ssc[128], ssf[128];
    int tid = threadIdx.x;
    if (tid < 128) {
        float mu = st[tid] * invN;
        float var = st[128 + tid] * invN - mu * mu;
        float rstd = rsqrtf(fmaxf(var, 0.f) + 1e-5f);
        float sc = rstd * gam[tid];
        ssc[tid] = sc;
        ssf[tid] = bet[tid] - mu * sc;
    }
    __syncthreads();
    int lane = tid & 63, w = tid >> 6;
    int m16 = lane & 15, quad = lane >> 4;
    int rowBase = blockIdx.y * 128;
    int colBase = blockIdx.x * 64;
    f32x4 acc[2][4] = {};
    for (int k0 = 0; k0 < 128; k0 += 32) {
        #pragma unroll
        for (int i = 0; i < 2; ++i) {
            int u = tid + i * 256;
            int r = u >> 2, g = u & 3;
            int c = k0 + g * 8;
            const float* p = &Hin[(rowBase + r) * 128 + c];
            float4 x = *(const float4*)p, y = *(const float4*)(p + 4);
            float h0 = fmaxf(x.x * ssc[c+0] + ssf[c+0], 0.f);
            float h1 = fmaxf(x.y * ssc[c+1] + ssf[c+1], 0.f);
            float h2 = fmaxf(x.z * ssc[c+2] + ssf[c+2], 0.f);
            float h3 = fmaxf(x.w * ssc[c+3] + ssf[c+3], 0.f);
            float h4 = fmaxf(y.x * ssc[c+4] + ssf[c+4], 0.f);
            float h5 = fmaxf(y.y * ssc[c+5] + ssf[c+5], 0.f);
            float h6 = fmaxf(y.z * ssc[c+6] + ssf[c+6], 0.f);
            float h7 = fmaxf(y.w * ssc[c+7] + ssf[c+7], 0.f);
            uint4 pk = make_uint4(pack2(h0, h1), pack2(h2, h3),
                                  pack2(h4, h5), pack2(h6, h7));
            int blk = (r >> 4) * 64 + (r & 15) * 4 + g;
            *(uint4*)&Asm[blk * 8] = pk;
        }
        {
            int n = tid >> 2, g = tid & 3;
            const float* p = &W[(colBase + n) * 128 + k0 + g * 8];
            float4 x = *(const float4*)p, y = *(const float4*)(p + 4);
            uint4 pk = make_uint4(pack2(x.x, x.y), pack2(x.z, x.w),
                                  pack2(y.x, y.y), pack2(y.z, y.w));
            int blk = (n >> 4) * 64 + (n & 15) * 4 + g;
            *(uint4*)&Bsm[blk * 8] = pk;
        }
        __syncthreads();
        bf16x8 a0 = *(const bf16x8*)&Asm[((2 * w + 0) * 64 + m16 * 4 + quad) * 8];
        bf16x8 a1 = *(const bf16x8*)&Asm[((2 * w + 1) * 64 + m16 * 4 + quad) * 8];
        #pragma unroll
        for (int ct = 0; ct < 4; ++ct) {
            bf16x8 bf = *(const bf16x8*)&Bsm[(ct * 64 + m16 * 4 + quad) * 8];
            acc[0][ct] = __builtin_amdgcn_mfma_f32_16x16x32_bf16(a0, bf, acc[0][ct], 0, 0, 0);
            acc[1][ct] = __builtin_amdgcn_mfma_f32_16x16x32_bf16(a1, bf, acc[1][ct], 0, 0, 0);
        }
        __syncthreads();
    }
    #pragma unroll
    for (int ct = 0; ct < 4; ++ct) {
        float bv = bias[colBase + ct * 16 + m16];
        #pragma unroll
        for (int rt = 0; rt < 2; ++rt)
            #pragma unroll
            for (int r = 0; r < 4; ++r) {
                int row = rowBase + (2 * w + rt) * 16 + quad * 4 + r;
                out[row * 128 + colBase + ct * 16 + m16] = acc[rt][ct][r] + bv;
            }
    }
}

extern "C" void kernel_launch(void* const* d_in, const int* in_sizes, int n_in,
                              void* d_out, int out_size, void* d_ws, size_t ws_size,
                              hipStream_t stream) {
    const float* pts_r1 = (const float*)d_in[0];   // (2,8192,3)
    const float* pts_r2 = (const float*)d_in[1];   // (2,4096,3)
    const float* pts_r4 = (const float*)d_in[2];   // (2,2048,3)
    const float* feat0  = (const float*)d_in[3];   // (16384,128)
    const float* feat1  = (const float*)d_in[4];   // (8192,128)
    const float* feat2  = (const float*)d_in[5];   // (4096,128)
    const float* w3a = (const float*)d_in[6];      // (128,256)
    const float* g3  = (const float*)d_in[7];
    const float* b3  = (const float*)d_in[8];
    const float* w3b = (const float*)d_in[9];      // (128,128)
    const float* bb3 = (const float*)d_in[10];
    const float* w4a = (const float*)d_in[11];     // (128,256)
    const float* g4  = (const float*)d_in[12];
    const float* b4  = (const float*)d_in[13];
    const float* w4b = (const float*)d_in[14];     // (128,128)
    const float* bb4 = (const float*)d_in[15];

    float* wsf = (float*)d_ws;
    float4* xyz1 = (float4*)(wsf + 0);        // 16384 pts
    float4* xyz2 = (float4*)(wsf + 65536);    // 8192 pts
    float4* xyz4 = (float4*)(wsf + 98304);    // 4096 pts
    float* f2i = wsf + 114688;                // 8192*128
    float* H1  = wsf + 1163264;               // 8192*128
    float* n3  = wsf + 2211840;               // 8192*128
    float* n3i = wsf + 114688;                // 16384*128 (over f2i+H1, both dead)
    float* H2  = wsf + 3260416;               // 16384*128
    float* st1 = wsf + 5357568;               // 256 (sum | sumsq)
    float* st2 = wsf + 5358080;               // 256

    // 1. prep: pad xyz, zero stat accumulators
    prep_kernel<<<112, 256, 0, stream>>>(pts_r1, pts_r2, pts_r4, xyz1, xyz2, xyz4, st1, st2);
    // 2. interp #1: feat2 (pts_r4) -> pts_r2 targets, CHUNK=64
    nn_interp_kernel<64><<<dim3(512, 2), 256, 0, stream>>>(xyz2, 4096, xyz4, 2048,
                                                           feat2, f2i);
    // 3. fnode 3
    gemm_a_kernel<<<dim3(2, 64), 256, 0, stream>>>(feat1, f2i, w3a, H1, st1);
    gemm_b_kernel<<<dim3(2, 64), 256, 0, stream>>>(H1, st1, g3, b3, 1.f / 8192.f,
                                                   w3b, bb3, n3);
    // 4. interp #2: n3 (pts_r2) -> pts_r1 targets, CHUNK=128
    nn_interp_kernel<128><<<dim3(1024, 2), 256, 0, stream>>>(xyz1, 8192, xyz2, 4096,
                                                             n3, n3i);
    // 5. fnode 4
    gemm_a_kernel<<<dim3(2, 128), 256, 0, stream>>>(feat0, n3i, w4a, H2, st2);
    gemm_b_kernel<<<dim3(2, 128), 256, 0, stream>>>(H2, st2, g4, b4, 1.f / 16384.f,
                                                    w4b, bb4, (float*)d_out);
}